// Round 11
// baseline (1830.703 us; speedup 1.0000x reference)
//
#include <hip/hip_runtime.h>
#include <math.h>

#define B_ 8
#define N_ 4096
#define K_ 20
#define KS_ 24          // approx/pool width; exact rescore trims to K_ (R3/R10-validated margin)
#define BN_ (B_*N_)

typedef __attribute__((ext_vector_type(8))) short bf16x8;
typedef __attribute__((ext_vector_type(4))) float f32x4;

// ---------------------------------------------------------------- utilities
__global__ void zero_kernel(float* p, int n)
{
    for (int e = threadIdx.x; e < n; e += 256) p[e] = 0.f;
}

// mean/rstd from accumulated sum/sumsq.  layout: [sum(H), sumsq(H), mean(H), rstd(H)]
__global__ void finalize_kernel(float* st, int H, float invCount)
{
    int t = threadIdx.x;
    if (t < H) {
        float mean = st[t] * invCount;
        float var  = fmaxf(st[H + t] * invCount - mean * mean, 0.f);
        st[2*H + t] = mean;
        st[3*H + t] = 1.f / sqrtf(var + 1e-5f);
    }
}

// ---------------------------------------------------------------- kNN, C=4 (approx-pool variant)
// R10-validated recipe: ballot rounds (value-min, tie -> min LANE) build a
// pool of KS_; the exact rescore4 re-establishes the reference (value, index)
// order.  Pool misses require >=5 bit-exact ties at the boundary (~never).
// DO NOT use DPP reduces (R9: mis-selects on gfx950).
__global__ __launch_bounds__(1024) void knn4_kernel(const float* __restrict__ x, int* __restrict__ idx24)
{
    __shared__ float4 xt[N_];
    const int b = blockIdx.y;
    const int t = threadIdx.x;
    const float4* xg = (const float4*)x + b*N_;
    for (int e = t; e < N_; e += 1024) xt[e] = xg[e];
    __syncthreads();
    const int w = t >> 6, L = t & 63;
    const int n = blockIdx.x*16 + w;
    const float4 q = xt[n];
    float d[64];
    #pragma unroll
    for (int s = 0; s < 64; ++s) {
        float4 v = xt[(s<<6) | L];
        float nn = v.x*v.x + v.y*v.y + v.z*v.z + v.w*v.w;
        float dp = q.x*v.x + q.y*v.y + q.z*v.z + q.w*v.w;
        d[s] = nn - 2.f*dp;   // |xn|^2 dropped: rank-equivalent
    }
    const float MX = 3.4e38f;
    float m1 = MX, m2 = MX; int i1 = 0, i2 = 0;
    #pragma unroll
    for (int j = 0; j < 64; ++j) {
        float v = d[j];
        bool c1 = v < m1, c2 = v < m2;
        m2 = c1 ? m1 : (c2 ? v : m2);
        i2 = c1 ? i1 : (c2 ? j : i2);
        m1 = c1 ? v : m1;
        i1 = c1 ? j : i1;
    }
    bool have2 = true;
    unsigned long long used = 0;
    int mywin = 0;
    for (int r = 0; r < KS_; ++r) {
        float bmin = m1;
        #pragma unroll
        for (int off = 32; off; off >>= 1)
            bmin = fminf(bmin, __shfl_xor(bmin, off));
        const unsigned long long tied = __ballot(m1 == bmin);
        const int winlane = (int)__ffsll((unsigned long long)tied) - 1;
        const int wslot = __shfl(i1, winlane);
        if (L == r) mywin = (wslot << 6) | winlane;
        if (L == winlane) {
            used |= 1ull << i1;
            if (have2) { m1 = m2; i1 = i2; have2 = false; }
            else {
                m1 = MX; m2 = MX; i1 = 0; i2 = 0;
                #pragma unroll
                for (int j = 0; j < 64; ++j) {
                    float v = ((used >> j) & 1ull) ? MX : d[j];
                    bool c1 = v < m1, c2 = v < m2;
                    m2 = c1 ? m1 : (c2 ? v : m2);
                    i2 = c1 ? i1 : (c2 ? j : i2);
                    m1 = c1 ? v : m1;
                    i1 = c1 ? j : i1;
                }
                have2 = true;
            }
        }
    }
    if (L < KS_) idx24[((size_t)b*N_ + n)*KS_ + L] = mywin;
}

// exact rescore of the C=4 pool: same dist expression as knn4, lexicographic
// (value, candidate-index) butterfly = reference jax top_k tie-break.
__global__ __launch_bounds__(256) void rescore4_kernel(const float* __restrict__ x,
                                                       const int* __restrict__ idx24, int* __restrict__ idxout)
{
    const int t = threadIdx.x, w = t >> 6, L = t & 63;
    const int p = blockIdx.x*4 + w;
    const int bbase = p & ~(N_-1);
    const float MX = 3.4e38f;
    float dv = MX; int di = 0x7fffffff;
    const float4 q = ((const float4*)x)[p];
    if (L < KS_) {
        const int ci = idx24[(size_t)p*KS_ + L];
        const float4 v = ((const float4*)x)[bbase + ci];
        float nn = v.x*v.x + v.y*v.y + v.z*v.z + v.w*v.w;
        float dp = q.x*v.x + q.y*v.y + q.z*v.z + q.w*v.w;
        dv = nn - 2.f*dp;
        di = ci;
    }
    int myfin = 0;
    for (int r = 0; r < K_; ++r) {
        float bv = dv; int bg = di;
        #pragma unroll
        for (int off = 32; off; off >>= 1) {
            float ov = __shfl_xor(bv, off);
            int   og = __shfl_xor(bg, off);
            bool tk = (ov < bv) || (ov == bv && og < bg);
            bv = tk ? ov : bv; bg = tk ? og : bg;
        }
        if (L == r) myfin = bg;
        if (di == bg) dv = MX;
    }
    if (L < K_) idxout[(size_t)p*K_ + L] = myfin;
}

// ---------------------------------------------------------------- fp32 -> bf16 RNE
static __device__ inline unsigned short f2bf(float f)
{
    unsigned u = __float_as_uint(f);
    unsigned r = (u + 0x7fffu + ((u >> 16) & 1u)) >> 16;   // RNE
    return (unsigned short)r;
}

// ---------------------------------------------------------------- kNN, C=64 via MFMA (split-bf16 Gram, approx)
// v4 structure (R5/R7/R10-validated): ballot selection rounds.
__global__ __launch_bounds__(1024, 4) void knn64v4_kernel(
    const unsigned short* __restrict__ Xh, const unsigned short* __restrict__ Xl,
    const float* __restrict__ nrm, int* __restrict__ idx24)
{
    __shared__ float dist[16*1024];   // exactly 64 KB
    const int b = blockIdx.y, t = threadIdx.x;
    const int w = t >> 6, L = t & 63;
    const int q0 = blockIdx.x * 16;
    const int m = L & 15, kq = (L >> 4) * 8;
    const size_t rowbase = (size_t)b * N_ * 64;

    const unsigned short* aph = Xh + rowbase + (size_t)(q0 + m)*64 + kq;
    const unsigned short* apl = Xl + rowbase + (size_t)(q0 + m)*64 + kq;
    const bf16x8 a_h0 = *(const bf16x8*)(aph);
    const bf16x8 a_h1 = *(const bf16x8*)(aph + 32);
    const bf16x8 a_l0 = *(const bf16x8*)(apl);
    const bf16x8 a_l1 = *(const bf16x8*)(apl + 32);

    float d[64];
    #pragma unroll
    for (int ck = 0; ck < 4; ++ck) {
        const int cq = ck * 1024;
        __syncthreads();
        for (int tt = 0; tt < 4; ++tt) {
            const int cbase = w*64 + tt*16;
            const unsigned short* bph = Xh + rowbase + (size_t)(cq + cbase + m)*64 + kq;
            const unsigned short* bpl = Xl + rowbase + (size_t)(cq + cbase + m)*64 + kq;
            bf16x8 b_h0 = *(const bf16x8*)(bph);
            bf16x8 b_h1 = *(const bf16x8*)(bph + 32);
            bf16x8 b_l0 = *(const bf16x8*)(bpl);
            bf16x8 b_l1 = *(const bf16x8*)(bpl + 32);
            f32x4 acc = {0.f, 0.f, 0.f, 0.f};
            acc = __builtin_amdgcn_mfma_f32_16x16x32_bf16(a_h0, b_h0, acc, 0, 0, 0);
            acc = __builtin_amdgcn_mfma_f32_16x16x32_bf16(a_h1, b_h1, acc, 0, 0, 0);
            acc = __builtin_amdgcn_mfma_f32_16x16x32_bf16(a_l0, b_h0, acc, 0, 0, 0);
            acc = __builtin_amdgcn_mfma_f32_16x16x32_bf16(a_l1, b_h1, acc, 0, 0, 0);
            acc = __builtin_amdgcn_mfma_f32_16x16x32_bf16(a_h0, b_l0, acc, 0, 0, 0);
            acc = __builtin_amdgcn_mfma_f32_16x16x32_bf16(a_h1, b_l1, acc, 0, 0, 0);
            const float nv = nrm[b*N_ + cq + cbase + m];
            #pragma unroll
            for (int r = 0; r < 4; ++r) {
                const int qrow = (L >> 4)*4 + r;   // C/D: row=(lane>>4)*4+reg
                dist[qrow*1024 + cbase + m] = nv - 2.f*acc[r];
            }
        }
        __syncthreads();
        #pragma unroll
        for (int s = 0; s < 16; ++s)
            d[ck*16 + s] = dist[w*1024 + (s<<6) + L];
    }

    const float MX = 3.4e38f;
    float m1 = MX, m2 = MX; int i1 = 0, i2 = 0;
    #pragma unroll
    for (int j = 0; j < 64; ++j) {
        float v = d[j];
        bool c1 = v < m1, c2 = v < m2;
        m2 = c1 ? m1 : (c2 ? v : m2);
        i2 = c1 ? i1 : (c2 ? j : i2);
        m1 = c1 ? v : m1;
        i1 = c1 ? j : i1;
    }
    bool have2 = true;
    unsigned long long used = 0;
    int mywin = 0;
    for (int r = 0; r < KS_; ++r) {
        float bmin = m1;
        #pragma unroll
        for (int off = 32; off; off >>= 1)
            bmin = fminf(bmin, __shfl_xor(bmin, off));
        const unsigned long long tied = __ballot(m1 == bmin);
        const int winlane = (int)__ffsll((unsigned long long)tied) - 1;
        const int wslot = __shfl(i1, winlane);
        if (L == r) mywin = (wslot << 6) | winlane;
        if (L == winlane) {
            used |= 1ull << i1;
            if (have2) { m1 = m2; i1 = i2; have2 = false; }
            else {
                m1 = MX; m2 = MX; i1 = 0; i2 = 0;
                #pragma unroll
                for (int j = 0; j < 64; ++j) {
                    float v = ((used >> j) & 1ull) ? MX : d[j];
                    bool c1 = v < m1, c2 = v < m2;
                    m2 = c1 ? m1 : (c2 ? v : m2);
                    i2 = c1 ? i1 : (c2 ? j : i2);
                    m1 = c1 ? v : m1;
                    i1 = c1 ? j : i1;
                }
                have2 = true;
            }
        }
    }
    if (L < KS_) idx24[((size_t)b*N_ + q0 + w)*KS_ + L] = mywin;
}

// ---------------------------------------------------------------- exact fp32 rescore of the C=64 pool
__global__ __launch_bounds__(256) void rescore_kernel(const float* __restrict__ x1, const float* __restrict__ nrm,
                                                      const int* __restrict__ idx24, int* __restrict__ idxout)
{
    const int t = threadIdx.x, w = t >> 6, L = t & 63;
    const int p = blockIdx.x*4 + w;
    const int bbase = p & ~(N_-1);
    const float MX = 3.4e38f;
    float dv = MX; int di = 0x7fffffff;
    if (L < KS_) {
        const int ci = idx24[(size_t)p*KS_ + L];
        const float4* qr = (const float4*)(x1 + (size_t)p*64);
        const float4* cr = (const float4*)(x1 + (size_t)(bbase + ci)*64);
        float dot = 0.f;
        #pragma unroll
        for (int i = 0; i < 16; ++i) {
            float4 a = qr[i], bx = cr[i];
            dot += a.x*bx.x + a.y*bx.y + a.z*bx.z + a.w*bx.w;
        }
        dv = nrm[bbase + ci] - 2.f*dot;
        di = ci;
    }
    int myfin = 0;
    for (int r = 0; r < K_; ++r) {
        float bv = dv; int bg = di;
        #pragma unroll
        for (int off = 32; off; off >>= 1) {
            float ov = __shfl_xor(bv, off);
            int   og = __shfl_xor(bg, off);
            bool tk = (ov < bv) || (ov == bv && og < bg);
            bv = tk ? ov : bv; bg = tk ? og : bg;
        }
        if (L == r) myfin = bg;
        if (di == bg) dv = MX;
    }
    if (L < K_) idxout[(size_t)p*K_ + L] = myfin;
}

// ---------------------------------------------------------------- P/Q precompute
__global__ __launch_bounds__(256) void pq1_kernel(const float* __restrict__ x, const float* __restrict__ W,
                                                  const float* __restrict__ b1,
                                                  float* __restrict__ P, float* __restrict__ Q)
{
    __shared__ float wd[256], wb[256];
    const int t = threadIdx.x;
    wd[t] = W[t] - W[256 + t];
    wb[t] = W[256 + t];
    __syncthreads();
    const int p = blockIdx.x*4 + (t >> 6), c = t & 63;
    const float4 xv = ((const float4*)x)[p];
    float Pv = b1[c] + xv.x*wd[c] + xv.y*wd[64+c] + xv.z*wd[128+c] + xv.w*wd[192+c];
    float Qv =         xv.x*wb[c] + xv.y*wb[64+c] + xv.z*wb[128+c] + xv.w*wb[192+c];
    P[p*64 + c] = Pv;
    Q[p*64 + c] = Qv;
}

__global__ __launch_bounds__(256) void pq2_kernel(const float* __restrict__ x1, const float* __restrict__ W,
                                                  const float* __restrict__ b1,
                                                  float* __restrict__ P, float* __restrict__ Q)
{
    __shared__ float wd[64*128], wb[64*128];
    const int t = threadIdx.x;
    for (int e = t; e < 8192; e += 256) {
        float wt = W[e], wbo = W[8192 + e];
        wd[e] = wt - wbo; wb[e] = wbo;
    }
    __syncthreads();
    const int pl = t >> 7, c = t & 127;
    const float b1v = b1[c];
    for (int p0 = blockIdx.x*2; p0 < BN_; p0 += gridDim.x*2) {
        const int p = p0 + pl;
        float Pv = b1v, Qv = 0.f;
        const float* xrow = x1 + p*64;
        #pragma unroll 8
        for (int k = 0; k < 64; ++k) {
            float xv = xrow[k];
            Pv += xv * wd[k*128 + c];
            Qv += xv * wb[k*128 + c];
        }
        P[p*128 + c] = Pv;
        Q[p*128 + c] = Qv;
    }
}

// ---------------------------------------------------------------- layer-1 BN stats
template<int HO>
__global__ __launch_bounds__(256) void stats_l1_kernel(const float* __restrict__ P, const float* __restrict__ Q,
                                                       const int* __restrict__ idx, float* __restrict__ stOut)
{
    constexpr int G = 256/HO;
    __shared__ float red[256], red2[256];
    const int t = threadIdx.x, c = t % HO, g = t / HO;
    float s = 0.f, s2 = 0.f;
    for (int p = blockIdx.x; p < BN_; p += gridDim.x) {
        const float Pv = P[p*HO + c];
        const int bbase = p & ~(N_-1);
        for (int j = g; j < K_; j += G) {
            int m = idx[p*K_ + j];
            float z = Pv + Q[(bbase + m)*HO + c];
            s += z; s2 += z*z;
        }
    }
    red[t] = s; red2[t] = s2;
    __syncthreads();
    if (t < HO) {
        float a = red[t], a2 = red2[t];
        #pragma unroll
        for (int q = 1; q < G; ++q) { a += red[q*HO + t]; a2 += red2[q*HO + t]; }
        atomicAdd(&stOut[t], a);
        atomicAdd(&stOut[HO + t], a2);
    }
}

// ---------------------------------------------------------------- EdgeConv layer-2, exact fp32 (conv1:
// output feeds flip-sensitive kNN2).  W2 staged TRANSPOSED with stride-68 rows
// (conflict-free per-lane ds_read_b128); h1 read as float4 broadcasts.  FMA
// sequence kept in the same c-ascending order (explicit fmaf) -> values
// bitwise-identical to the R10-passing scalar loop.
__global__ __launch_bounds__(256) void conv_l2_64_kernel(
    const float* __restrict__ P, const float* __restrict__ Q, const int* __restrict__ idx,
    const float* __restrict__ st1, const float* __restrict__ g1, const float* __restrict__ be1,
    const float* __restrict__ w2, const float* __restrict__ b2,
    float* __restrict__ zmax, float* __restrict__ zmin, float* __restrict__ stOut)
{
    __shared__ __align__(16) float w2t[64*68];
    __shared__ __align__(16) float h1s[K_*64];
    __shared__ float redA[256], redB[256];
    const int t = threadIdx.x;
    for (int e = t; e < 4096; e += 256) {
        int cl = e >> 6, c = e & 63;
        w2t[cl*68 + c] = w2[c*64 + cl];
    }
    const int cA = t & 63;
    const float ac = st1[192 + cA] * g1[cA];
    const float bc = be1[cA] - st1[128 + cA] * ac;
    const int c2l = t & 63, jh = t >> 6;
    const float b2v = b2[c2l];
    float ssum = 0.f, ssq = 0.f;
    for (int p = blockIdx.x; p < BN_; p += gridDim.x) {
        __syncthreads();
        const int bbase = p & ~(N_-1);
        const float Pv = P[p*64 + cA];
        for (int e = t; e < K_*64; e += 256) {
            int j = e >> 6;
            int m = idx[p*K_ + j];
            float z = Pv + Q[(bbase + m)*64 + cA];
            h1s[e] = fmaxf(z*ac + bc, 0.f);
        }
        __syncthreads();
        float acc[5];
        #pragma unroll
        for (int q = 0; q < 5; ++q) acc[q] = b2v;
        #pragma unroll 4
        for (int c4 = 0; c4 < 16; ++c4) {
            const float4 wv = *(const float4*)&w2t[c2l*68 + c4*4];
            #pragma unroll
            for (int q = 0; q < 5; ++q) {
                const float4 hv = *(const float4*)&h1s[(jh + q*4)*64 + c4*4];
                acc[q] = fmaf(hv.x, wv.x, acc[q]);
                acc[q] = fmaf(hv.y, wv.y, acc[q]);
                acc[q] = fmaf(hv.z, wv.z, acc[q]);
                acc[q] = fmaf(hv.w, wv.w, acc[q]);
            }
        }
        float mx = acc[0], mn = acc[0];
        #pragma unroll
        for (int q = 0; q < 5; ++q) {
            mx = fmaxf(mx, acc[q]); mn = fminf(mn, acc[q]);
            ssum += acc[q]; ssq += acc[q]*acc[q];
        }
        redA[t] = mx; redB[t] = mn;
        __syncthreads();
        if (t < 64) {
            float M = redA[t], Mn = redB[t];
            #pragma unroll
            for (int g = 1; g < 4; ++g) { M = fmaxf(M, redA[g*64 + t]); Mn = fminf(Mn, redB[g*64 + t]); }
            zmax[p*64 + t] = M;
            zmin[p*64 + t] = Mn;
        }
    }
    __syncthreads();
    redA[t] = ssum; redB[t] = ssq;
    __syncthreads();
    if (t < 64) {
        float s = redA[t], s2 = redB[t];
        #pragma unroll
        for (int g = 1; g < 4; ++g) { s += redA[g*64 + t]; s2 += redB[g*64 + t]; }
        atomicAdd(&stOut[t], s);
        atomicAdd(&stOut[64 + t], s2);
    }
}

// conv1 finalize FUSED with split-bf16 prep + row norms (wave == row).
// Bitwise-identical to the old conv_fin<64> + prep64 pair.
__global__ __launch_bounds__(256) void conv_fin1_kernel(
    const float* __restrict__ zmax, const float* __restrict__ zmin,
    const float* __restrict__ st2, const float* __restrict__ g2, const float* __restrict__ be2,
    float* __restrict__ out, unsigned short* __restrict__ Xh, unsigned short* __restrict__ Xl,
    float* __restrict__ nrm)
{
    const int t = threadIdx.x;
    const int e = blockIdx.x*256 + t;
    const int c = e & 63;
    float g = g2[c];
    float a = st2[192 + c] * g;
    float sel = (g >= 0.f) ? zmax[e] : zmin[e];
    float v = fmaxf((sel - st2[128 + c]) * a + be2[c], 0.f);
    out[e] = v;
    unsigned short h = f2bf(v);
    float hf = __uint_as_float((unsigned)h << 16);
    Xh[e] = h;
    Xl[e] = f2bf(v - hf);
    float s = v * v;
    #pragma unroll
    for (int off = 32; off; off >>= 1) s += __shfl_xor(s, off);
    if ((t & 63) == 0) nrm[e >> 6] = s;
}

// ---------------------------------------------------------------- W2^T split-bf16 prep
__global__ __launch_bounds__(256) void prep_w2t_kernel(const float* __restrict__ W,
                                                       unsigned short* __restrict__ wh,
                                                       unsigned short* __restrict__ wl, int HO)
{
    const int e = blockIdx.x*256 + threadIdx.x;   // e = k*HO + c
    const int k = e / HO, c = e % HO;
    const float v = W[e];
    unsigned short h = f2bf(v);
    float hf = __uint_as_float((unsigned)h << 16);
    wh[c*HO + k] = h;
    wl[c*HO + k] = f2bf(v - hf);
}

// ---------------------------------------------------------------- EdgeConv layer-2 via MFMA (split-bf16)
// conv2 only: output feeds the classifier (value-continuous), bf16-split safe.
template<int HO>
__global__ __launch_bounds__(256) void conv_l2_mfma_kernel(
    const float* __restrict__ P, const float* __restrict__ Q, const int* __restrict__ idx,
    const float* __restrict__ st1, const float* __restrict__ g1, const float* __restrict__ be1,
    const unsigned short* __restrict__ w2h, const unsigned short* __restrict__ w2l,
    const float* __restrict__ b2,
    float* __restrict__ zmax, float* __restrict__ zmin, float* __restrict__ stOut)
{
    constexpr int HOP = HO + 8;
    constexpr int CDP = HO + 1;
    constexpr int CTW = HO / 64;
    constexpr int KSn = HO / 32;
    constexpr int HSH = (HO == 128) ? 7 : 6;
    __shared__ __align__(16) short hs[2*80*HOP];
    __shared__ int sidx[80];
    float* cd = (float*)hs;

    const int t = threadIdx.x, w = t >> 6, L = t & 63;
    const int m16 = L & 15, q4 = L >> 4;

    const int kT = t & (HO - 1);
    const float ac = st1[3*HO + kT] * g1[kT];
    const float bc = be1[kT] - st1[2*HO + kT] * ac;

    bf16x8 Bh[CTW][KSn], Bl[CTW][KSn];
    #pragma unroll
    for (int ctl = 0; ctl < CTW; ++ctl)
        #pragma unroll
        for (int ks = 0; ks < KSn; ++ks) {
            const int c  = w*16*CTW + ctl*16 + m16;
            const int k0 = ks*32 + q4*8;
            Bh[ctl][ks] = *(const bf16x8*)(w2h + c*HO + k0);
            Bl[ctl][ks] = *(const bf16x8*)(w2l + c*HO + k0);
        }

    const float b2c = (t < HO) ? b2[t] : 0.f;
    float ssum = 0.f, ssq = 0.f;

    for (int p0 = blockIdx.x*4; p0 < BN_; p0 += gridDim.x*4) {
        const int bbase = p0 & ~(N_-1);
        __syncthreads();
        if (t < 80) sidx[t] = idx[p0*K_ + t];
        __syncthreads();
        for (int e = t; e < 80*HO; e += 256) {
            const int r  = e >> HSH;
            const int pl = (r*3277) >> 16;     // r/20 for r<80
            const int mI = sidx[r];
            float z = P[(size_t)(p0+pl)*HO + kT] + Q[(size_t)(bbase+mI)*HO + kT];
            float h = fmaxf(z*ac + bc, 0.f);
            unsigned short hh = f2bf(h);
            float hf = __uint_as_float((unsigned)hh << 16);
            unsigned short hl = f2bf(h - hf);
            hs[r*HOP + kT] = (short)hh;
            hs[80*HOP + r*HOP + kT] = (short)hl;
        }
        __syncthreads();
        f32x4 acc[5][CTW];
        #pragma unroll
        for (int rt = 0; rt < 5; ++rt)
            #pragma unroll
            for (int ctl = 0; ctl < CTW; ++ctl)
                acc[rt][ctl] = (f32x4){0.f, 0.f, 0.f, 0.f};
        #pragma unroll
        for (int rt = 0; rt < 5; ++rt)
            #pragma unroll
            for (int ks = 0; ks < KSn; ++ks) {
                const short* ap = hs + (rt*16 + m16)*HOP + ks*32 + q4*8;
                bf16x8 Ah = *(const bf16x8*)ap;
                bf16x8 Al = *(const bf16x8*)(ap + 80*HOP);
                #pragma unroll
                for (int ctl = 0; ctl < CTW; ++ctl) {
                    acc[rt][ctl] = __builtin_amdgcn_mfma_f32_16x16x32_bf16(Ah, Bh[ctl][ks], acc[rt][ctl], 0, 0, 0);
                    acc[rt][ctl] = __builtin_amdgcn_mfma_f32_16x16x32_bf16(Al, Bh[ctl][ks], acc[rt][ctl], 0, 0, 0);
                    acc[rt][ctl] = __builtin_amdgcn_mfma_f32_16x16x32_bf16(Ah, Bl[ctl][ks], acc[rt][ctl], 0, 0, 0);
                }
            }
        __syncthreads();
        #pragma unroll
        for (int rt = 0; rt < 5; ++rt)
            #pragma unroll
            for (int ctl = 0; ctl < CTW; ++ctl) {
                const int col = w*16*CTW + ctl*16 + m16;
                #pragma unroll
                for (int ri = 0; ri < 4; ++ri) {
                    const int row = rt*16 + q4*4 + ri;
                    cd[row*CDP + col] = acc[rt][ctl][ri];
                }
            }
        __syncthreads();
        if (t < HO) {
            #pragma unroll
            for (int pl = 0; pl < 4; ++pl) {
                float mx = -3.4e38f, mn = 3.4e38f;
                #pragma unroll
                for (int j = 0; j < K_; ++j) {
                    float v = cd[(pl*20 + j)*CDP + t] + b2c;
                    mx = fmaxf(mx, v); mn = fminf(mn, v);
                    ssum += v; ssq += v*v;
                }
                zmax[(size_t)(p0+pl)*HO + t] = mx;
                zmin[(size_t)(p0+pl)*HO + t] = mn;
            }
        }
    }
    if (t < HO) {
        atomicAdd(&stOut[t], ssum);
        atomicAdd(&stOut[HO + t], ssq);
    }
}

// max_j relu(BN(z)) = relu(BN(max_j z)) for gamma>=0, min for gamma<0
template<int HO>
__global__ __launch_bounds__(256) void conv_fin_kernel(
    const float* __restrict__ zmax, const float* __restrict__ zmin,
    const float* __restrict__ st2, const float* __restrict__ g2, const float* __restrict__ be2,
    float* __restrict__ out)
{
    int e = blockIdx.x*256 + threadIdx.x;
    int c = e & (HO-1);
    float g = g2[c];
    float a = st2[3*HO + c] * g;
    float sel = (g >= 0.f) ? zmax[e] : zmin[e];
    out[e] = fmaxf((sel - st2[2*HO + c]) * a + be2[c], 0.f);
}

// ---------------------------------------------------------------- classifier
__global__ __launch_bounds__(256) void cls1_kernel(
    const float* __restrict__ x1, const float* __restrict__ x2f,
    const float* __restrict__ W, const float* __restrict__ b1,
    float* __restrict__ z, float* __restrict__ stOut)
{
    __shared__ float ws[192*64];
    __shared__ float xr[4*192];
    __shared__ float red[256], red2[256];
    const int t = threadIdx.x, cy = blockIdx.y;
    for (int e = t; e < 192*64; e += 256) {
        int c = e >> 6, cl = e & 63;
        ws[e] = W[c*128 + cy*64 + cl];
    }
    const int pl = t >> 6, c2l = t & 63;
    const float b1v = b1[cy*64 + c2l];
    float ssum = 0.f, ssq = 0.f;
    for (int p0 = blockIdx.x*4; p0 < BN_; p0 += gridDim.x*4) {
        __syncthreads();
        for (int l = t; l < 4*192; l += 256) {
            int pp = l / 192, cc = l % 192;
            xr[l] = (cc < 64) ? x1[(p0+pp)*64 + cc] : x2f[(p0+pp)*128 + cc - 64];
        }
        __syncthreads();
        float acc = b1v;
        const float* xx = xr + pl*192;
        #pragma unroll 8
        for (int c = 0; c < 192; ++c) acc += xx[c] * ws[c*64 + c2l];
        z[(p0+pl)*128 + cy*64 + c2l] = acc;
        ssum += acc; ssq += acc*acc;
    }
    __syncthreads();
    red[t] = ssum; red2[t] = ssq;
    __syncthreads();
    if (t < 64) {
        float s = red[t], s2 = red2[t];
        #pragma unroll
        for (int g = 1; g < 4; ++g) { s += red[g*64 + t]; s2 += red2[g*64 + t]; }
        atomicAdd(&stOut[cy*64 + t], s);
        atomicAdd(&stOut[128 + cy*64 + t], s2);
    }
}

__global__ __launch_bounds__(256) void cls_fin_kernel(
    const float* __restrict__ z, const float* __restrict__ st,
    const float* __restrict__ g, const float* __restrict__ be,
    const float* __restrict__ w2, const float* __restrict__ b2,
    float* __restrict__ out)
{
    const int t = threadIdx.x, w = t >> 6, L = t & 63;
    const int p = blockIdx.x*4 + w;
    float s = 0.f;
    #pragma unroll
    for (int h = 0; h < 2; ++h) {
        int c = L + h*64;
        float v = (z[p*128 + c] - st[256 + c]) * st[384 + c] * g[c] + be[c];
        s += fmaxf(v, 0.f) * w2[c];
    }
    #pragma unroll
    for (int off = 32; off; off >>= 1) s += __shfl_xor(s, off);
    if (L == 0) out[p] = s + b2[0];
}

// ---------------------------------------------------------------- launch
extern "C" void kernel_launch(void* const* d_in, const int* in_sizes, int n_in,
                              void* d_out, int out_size, void* d_ws, size_t ws_size,
                              hipStream_t stream)
{
    const float* x      = (const float*)d_in[0];
    const float* c1_w1  = (const float*)d_in[1];
    const float* c1_b1  = (const float*)d_in[2];
    const float* c1_g1  = (const float*)d_in[3];
    const float* c1_be1 = (const float*)d_in[4];
    const float* c1_w2  = (const float*)d_in[5];
    const float* c1_b2  = (const float*)d_in[6];
    const float* c1_g2  = (const float*)d_in[7];
    const float* c1_be2 = (const float*)d_in[8];
    const float* c2_w1  = (const float*)d_in[9];
    const float* c2_b1  = (const float*)d_in[10];
    const float* c2_g1  = (const float*)d_in[11];
    const float* c2_be1 = (const float*)d_in[12];
    const float* c2_w2  = (const float*)d_in[13];
    const float* c2_b2  = (const float*)d_in[14];
    const float* c2_g2  = (const float*)d_in[15];
    const float* c2_be2 = (const float*)d_in[16];
    const float* cls_w1 = (const float*)d_in[17];
    const float* cls_b1 = (const float*)d_in[18];
    const float* cls_g1 = (const float*)d_in[19];
    const float* cls_be1= (const float*)d_in[20];
    const float* cls_w2 = (const float*)d_in[21];
    const float* cls_b2 = (const float*)d_in[22];
    (void)in_sizes; (void)n_in; (void)out_size; (void)ws_size;

    char* ws = (char*)d_ws;
    size_t off = 0;
    auto alloc = [&](size_t bytes) { char* p = ws + off; off += (bytes + 255) & ~255ull; return p; };
    float* A    = (float*)alloc((size_t)16<<20);   // P1 -> Xh/Xl (conv_fin1..knn64v4) -> P2 -> zcls
    float* Bq   = (float*)alloc((size_t)16<<20);   // Q1 -> Q2
    float* zmax = (float*)alloc((size_t)16<<20);
    float* zmin = (float*)alloc((size_t)16<<20);
    float* x1b  = (float*)alloc((size_t)8<<20);
    float* x2b  = (float*)alloc((size_t)16<<20);   // also hosts idx24 pools (both kNN phases)
    int*   idx  = (int*)  alloc((size_t)BN_*K_*4); // idx1 -> idx2
    float* nrm  = (float*)alloc((size_t)BN_*4);
    float* st   = (float*)alloc((size_t)5*512*4);
    unsigned short* w2th = (unsigned short*)alloc((size_t)128*128*2);  // W2^T hi
    unsigned short* w2tl = (unsigned short*)alloc((size_t)128*128*2);  // W2^T lo
    float *st0 = st, *st1 = st+512, *st2 = st+1024, *st3 = st+1536, *st4 = st+2048;

    // split-bf16 feature buffers alias A (P1 dead after conv_l2_64; pq2
    // rewrites A only after knn64v4 completes).  NOT zmax: conv_fin1 reads
    // zmax/zmin while writing Xh/Xl (would race).
    unsigned short* Xh = (unsigned short*)A;                       // 4 MB
    unsigned short* Xl = (unsigned short*)((char*)A + (4<<20));    // 4 MB
    int* idx24 = (int*)x2b;

    zero_kernel<<<1, 256, 0, stream>>>(st, 5*512);

    // ---- EdgeConv 1 (exact fp32 conv: x1b feeds flip-sensitive kNN2)
    knn4_kernel<<<dim3(N_/16, B_), 1024, 0, stream>>>(x, idx24);
    rescore4_kernel<<<BN_/4, 256, 0, stream>>>(x, idx24, idx);
    pq1_kernel<<<BN_/4, 256, 0, stream>>>(x, c1_w1, c1_b1, A, Bq);
    stats_l1_kernel<64><<<2048, 256, 0, stream>>>(A, Bq, idx, st0);
    finalize_kernel<<<1, 128, 0, stream>>>(st0, 64, 1.f/655360.f);
    conv_l2_64_kernel<<<2048, 256, 0, stream>>>(A, Bq, idx, st0, c1_g1, c1_be1, c1_w2, c1_b2, zmax, zmin, st1);
    finalize_kernel<<<1, 128, 0, stream>>>(st1, 64, 1.f/655360.f);
    conv_fin1_kernel<<<BN_*64/256, 256, 0, stream>>>(zmax, zmin, st1, c1_g2, c1_be2, x1b, Xh, Xl, nrm);

    // ---- EdgeConv 2 (MFMA conv: x2b only feeds classifier)
    knn64v4_kernel<<<dim3(N_/16, B_), 1024, 0, stream>>>(Xh, Xl, nrm, idx24);
    rescore_kernel<<<BN_/4, 256, 0, stream>>>(x1b, nrm, idx24, idx);
    pq2_kernel<<<1024, 256, 0, stream>>>(x1b, c2_w1, c2_b1, A, Bq);
    stats_l1_kernel<128><<<2048, 256, 0, stream>>>(A, Bq, idx, st2);
    finalize_kernel<<<1, 128, 0, stream>>>(st2, 128, 1.f/655360.f);
    prep_w2t_kernel<<<128*128/256, 256, 0, stream>>>(c2_w2, w2th, w2tl, 128);
    conv_l2_mfma_kernel<128><<<2048, 256, 0, stream>>>(A, Bq, idx, st2, c2_g1, c2_be1, w2th, w2tl, c2_b2, zmax, zmin, st3);
    finalize_kernel<<<1, 128, 0, stream>>>(st3, 128, 1.f/655360.f);
    conv_fin_kernel<128><<<BN_*128/256, 256, 0, stream>>>(zmax, zmin, st3, c2_g2, c2_be2, x2b);

    // ---- classifier
    cls1_kernel<<<dim3(512,2), 256, 0, stream>>>(x1b, x2b, cls_w1, cls_b1, A, st4);
    finalize_kernel<<<1, 128, 0, stream>>>(st4, 128, 1.f/32768.f);
    cls_fin_kernel<<<BN_/4, 256, 0, stream>>>(A, st4, cls_g1, cls_be1, cls_w2, cls_b2, (float*)d_out);
}